// Round 6
// baseline (187.667 us; speedup 1.0000x reference)
//
#include <hip/hip_runtime.h>
#include <hip/hip_bf16.h>
#include <stdint.h>

#define KAUG 192   // 128 LoRA cols + 8 gate cols + 56 zero pad (multiple of 64)
#define M_ROWS 16384

typedef __attribute__((ext_vector_type(8))) __bf16 bf16x8;
typedef __attribute__((ext_vector_type(4))) float f32x4;

__device__ __forceinline__ unsigned short f2b(float f) {
  unsigned int u = __builtin_bit_cast(unsigned int, f);
  u = (u + 0x7fffu + ((u >> 16) & 1u)) >> 16;
  return (unsigned short)u;
}

__device__ __forceinline__ void lds_load16(const unsigned short* g, unsigned short* l) {
  __builtin_amdgcn_global_load_lds(
      (const __attribute__((address_space(1))) void*)g,
      (__attribute__((address_space(3))) void*)l, 16, 0, 0);
}

// ---------------- prep kernels ----------------

__global__ void gate_kernel(const int* __restrict__ dom, const float* __restrict__ emb,
                            const float* __restrict__ gW, const float* __restrict__ gb,
                            float* __restrict__ gate) {
  int i = blockIdx.x * blockDim.x + threadIdx.x;
  int d = dom[i];
  float e0 = emb[d*4+0], e1 = emb[d*4+1], e2 = emb[d*4+2], e3 = emb[d*4+3];
  float l[8]; float mx = -1e30f;
#pragma unroll
  for (int j = 0; j < 8; j++) {
    l[j] = e0*gW[j] + e1*gW[8+j] + e2*gW[16+j] + e3*gW[24+j] + gb[j];
    mx = fmaxf(mx, l[j]);
  }
  float s = 0.f;
#pragma unroll
  for (int j = 0; j < 8; j++) { l[j] = __expf(l[j] - mx); s += l[j]; }
  float inv = 1.0f / s;
#pragma unroll
  for (int j = 0; j < 8; j++) gate[i*8+j] = l[j] * inv;
}

__global__ void f32_to_bf16_vec(const float* __restrict__ in, unsigned short* __restrict__ out, int n4) {
  int i = blockIdx.x * blockDim.x + threadIdx.x;
  if (i >= n4) return;
  float4 v = ((const float4*)in)[i];
  ushort4 o;
  o.x = f2b(v.x); o.y = f2b(v.y); o.z = f2b(v.z); o.w = f2b(v.w);
  ((ushort4*)out)[i] = o;
}

// LDS-tiled transpose: Wt[n*K+k] = bf16(W[k*N+n]); both sides coalesced.
__global__ void build_wt_t(const float* __restrict__ W, unsigned short* __restrict__ Wt,
                           int K, int N) {
  __shared__ float tl[32][33];
  int n0 = blockIdx.x * 32, k0 = blockIdx.y * 32;
  int tx = threadIdx.x & 31, ty = threadIdx.x >> 5;   // 256 thr: ty 0..7
#pragma unroll
  for (int i = 0; i < 32; i += 8)
    tl[ty + i][tx] = W[(long)(k0 + ty + i) * N + n0 + tx];
  __syncthreads();
#pragma unroll
  for (int i = 0; i < 32; i += 8)
    Wt[(long)(n0 + ty + i) * K + k0 + tx] = f2b(tl[tx][ty + i]);
}

// Aft[(e*16+r)*P + p] = bf16(A[e][p][r]); LDS-tiled, coalesced.
__global__ void build_aft_t(const float* __restrict__ A, unsigned short* __restrict__ Aft, int P) {
  __shared__ float tl[64][17];
  int e = blockIdx.y; long p0 = (long)blockIdx.x * 64;
  int t = threadIdx.x;
#pragma unroll
  for (int pass = 0; pass < 4; pass++) {
    int idx = t + pass * 256;           // 0..1023
    int pl = idx >> 4, r = idx & 15;
    tl[pl][r] = A[((long)e * P + p0 + pl) * 16 + r];
  }
  __syncthreads();
#pragma unroll
  for (int pass = 0; pass < 4; pass++) {
    int idx = t + pass * 256;
    int r = idx >> 6, pl = idx & 63;
    Aft[(long)(e * 16 + r) * P + p0 + pl] = f2b(tl[pl][r]);
  }
}

// Bft[n*KAUG + kk]: kk<128 -> B_flat[kk*H+n]; kk in [128,136) -> lb[kk-128][n]; else 0.
__global__ void build_bft_t(const float* __restrict__ Bm, const float* __restrict__ lb,
                            unsigned short* __restrict__ Bft, int H) {
  __shared__ float tl[32][33];
  int n0 = blockIdx.x * 32, kk0 = blockIdx.y * 32;
  int tx = threadIdx.x & 31, ty = threadIdx.x >> 5;
#pragma unroll
  for (int i = 0; i < 32; i += 8) {
    int kk = kk0 + ty + i;
    float v;
    if (kk < 128)       v = Bm[(long)kk * H + n0 + tx];
    else if (kk < 136)  v = lb[(long)(kk - 128) * H + n0 + tx];
    else                v = 0.f;
    tl[ty + i][tx] = v;
  }
  __syncthreads();
#pragma unroll
  for (int i = 0; i < 32; i += 8)
    Bft[(long)(n0 + ty + i) * KAUG + kk0 + tx] = f2b(tl[tx][ty + i]);
}

// tg[b][128+j]: j<8 -> gate[b][j]; j in [8,64) -> 0
__global__ void aug_fill(const float* __restrict__ gate, unsigned short* __restrict__ tg) {
  int i = blockIdx.x * blockDim.x + threadIdx.x;  // M*64 threads
  int j = i & 63; int b = i >> 6;
  float v = (j < 8) ? gate[b*8 + j] : 0.f;
  tg[(long)b * KAUG + 128 + j] = f2b(v);
}

// ---------------- 2-phase 64-row GEMM (x@A only) ----------------
template<int MREP>
__global__ __launch_bounds__(256)
void gemm2ph(const unsigned short* __restrict__ A1, int lda1, int K1,
             const unsigned short* __restrict__ Bt1,
             const float* __restrict__ gate,
             void* __restrict__ outp, int ldout) {
  constexpr int BM = MREP * 32;
  __shared__ __attribute__((aligned(16))) unsigned short As[2][BM * 32];
  __shared__ __attribute__((aligned(16))) unsigned short Bs[2][128 * 32];
  const int t = threadIdx.x;
  const int lane = t & 63, wave = t >> 6;
  const int wr = wave >> 1, wc = wave & 1;
  const int row0 = blockIdx.x * BM, col0 = blockIdx.y * 128;
  const int rl = lane & 15, kg = lane >> 4;
  const int kswz = kg ^ ((rl >> 1) & 3);
  const int sr0 = t >> 2;
  const int sc0 = (((t & 3) ^ ((sr0 >> 1) & 3))) * 8;

  f32x4 acc[MREP][4];
#pragma unroll
  for (int m = 0; m < MREP; m++)
#pragma unroll
    for (int n = 0; n < 4; n++) acc[m][n] = (f32x4){0.f, 0.f, 0.f, 0.f};

  auto stage = [&](int buf, int kt) {
    unsigned short* ab = &As[buf][0];
    unsigned short* bb = &Bs[buf][0];
    lds_load16(A1 + (long)(row0 + sr0) * lda1 + kt + sc0, ab + t * 8);
    if constexpr (MREP == 4)
      lds_load16(A1 + (long)(row0 + sr0 + 64) * lda1 + kt + sc0, ab + t * 8 + 2048);
    lds_load16(Bt1 + (long)(col0 + sr0) * K1 + kt + sc0, bb + t * 8);
    lds_load16(Bt1 + (long)(col0 + sr0 + 64) * K1 + kt + sc0, bb + t * 8 + 2048);
  };

  stage(0, 0);
  __syncthreads();
  int cur = 0;
  for (int kt = 0; kt < K1; kt += 32) {
    if (kt + 32 < K1) stage(cur ^ 1, kt + 32);
    bf16x8 af[MREP], bfv[4];
#pragma unroll
    for (int m = 0; m < MREP; m++)
      af[m] = *(const bf16x8*)&As[cur][(wr * (MREP * 16) + m * 16 + rl) * 32 + kswz * 8];
#pragma unroll
    for (int n = 0; n < 4; n++)
      bfv[n] = *(const bf16x8*)&Bs[cur][(wc * 64 + n * 16 + rl) * 32 + kswz * 8];
    __builtin_amdgcn_s_setprio(1);
#pragma unroll
    for (int m = 0; m < MREP; m++)
#pragma unroll
      for (int n = 0; n < 4; n++)
        acc[m][n] = __builtin_amdgcn_mfma_f32_16x16x32_bf16(af[m], bfv[n], acc[m][n], 0, 0, 0);
    __builtin_amdgcn_s_setprio(0);
    __syncthreads();
    cur ^= 1;
  }

#pragma unroll
  for (int m = 0; m < MREP; m++)
#pragma unroll
    for (int n = 0; n < 4; n++)
#pragma unroll
      for (int j = 0; j < 4; j++) {
        int row = row0 + wr * (MREP * 16) + m * 16 + kg * 4 + j;
        int col = col0 + wc * 64 + n * 16 + rl;
        float v = acc[m][n][j] * gate[row * 8 + (col >> 4)];
        ((unsigned short*)outp)[(long)row * ldout + col] = f2b(v);
      }
}

// ---------------- fine-phase 128-wide GEMM (kept for L2) ----------------
template<int MODE, int BM>
__global__ __launch_bounds__(512)
void gemm_mn(const unsigned short* __restrict__ A1, int lda1, int K1,
             const unsigned short* __restrict__ A2, int lda2, int K2,
             const unsigned short* __restrict__ Bt1, int ldb1,
             const unsigned short* __restrict__ Bt2, int ldb2,
             const float* __restrict__ bias,
             void* __restrict__ outp, int ldout) {
  constexpr int MFRAG = BM / 32;
  constexpr int ATOT = BM * 64;
  constexpr int BTOT = 128 * 64;
  constexpr int LA = BM / 64;
  constexpr int L = LA + 2;
  __shared__ __attribute__((aligned(16))) unsigned short lds[3 * ATOT + 3 * BTOT];

  const int t = threadIdx.x;
  const int lane = t & 63, wave = t >> 6;
  const int wr = wave >> 2, wc = wave & 3;
  const int rl = lane & 15, kg = lane >> 4;
  const int row0 = blockIdx.x * BM, col0 = blockIdx.y * 128;

  const int sr = t >> 3;
  const int sk = ((t & 7) ^ (sr & 7)) * 8;

  f32x4 acc[MFRAG][2];
#pragma unroll
  for (int m = 0; m < MFRAG; m++)
#pragma unroll
    for (int n = 0; n < 2; n++) acc[m][n] = (f32x4){0.f, 0.f, 0.f, 0.f};

  auto stageA = [&](int buf, int kt) {
    const unsigned short* src; long ld; int kl;
    if (kt < K1) { src = A1; ld = lda1; kl = kt; }
    else         { src = A2; ld = lda2; kl = kt - K1; }
    unsigned short* d = &lds[buf * ATOT + t * 8];
    const unsigned short* s = src + (long)(row0 + sr) * ld + kl + sk;
#pragma unroll
    for (int i = 0; i < LA; i++)
      lds_load16(s + (long)(i * 64) * ld, d + i * 4096);
  };
  auto stageB = [&](int buf, int kt) {
    const unsigned short* src; long ld; int kl;
    if (kt < K1) { src = Bt1; ld = ldb1; kl = kt; }
    else         { src = Bt2; ld = ldb2; kl = kt - K1; }
    unsigned short* d = &lds[3 * ATOT + buf * BTOT + t * 8];
    const unsigned short* s = src + (long)(col0 + sr) * ld + kl + sk;
    lds_load16(s, d);
    lds_load16(s + 64 * ld, d + 4096);
  };
  auto ldA = [&](int buf, int mg, int ks) {
    int lr = wr * (BM / 2) + mg * 16 + rl;
    int sc = (ks * 4 + kg) ^ (lr & 7);
    return *(const bf16x8*)&lds[buf * ATOT + lr * 64 + sc * 8];
  };
  auto ldB = [&](int buf, int n, int ks) {
    int cr = wc * 32 + n * 16 + rl;
    int sc = (ks * 4 + kg) ^ (cr & 7);
    return *(const bf16x8*)&lds[3 * ATOT + buf * BTOT + cr * 64 + sc * 8];
  };

  const int Ktot = K1 + K2;
  const int NT = Ktot / 64;

  stageA(0, 0); stageB(0, 0);
  stageA(1, 64); stageB(1, 64);
  if constexpr (L == 6) asm volatile("s_waitcnt vmcnt(6)" ::: "memory");
  else                  asm volatile("s_waitcnt vmcnt(4)" ::: "memory");
  __builtin_amdgcn_s_barrier();

  int bcur = 0;
  bf16x8 Bfv[2][2];
  for (int tt = 0; tt < NT; ++tt) {
    int bpf = bcur + 2; if (bpf > 2) bpf -= 3;
    const bool pf = (tt + 2 < NT);
    bf16x8 Af[MFRAG / 2][2];
#pragma unroll
    for (int m = 0; m < MFRAG / 2; m++) { Af[m][0] = ldA(bcur, m, 0); Af[m][1] = ldA(bcur, m, 1); }
#pragma unroll
    for (int n = 0; n < 2; n++) { Bfv[n][0] = ldB(bcur, n, 0); Bfv[n][1] = ldB(bcur, n, 1); }
    if (pf) stageA(bpf, (tt + 2) * 64);
    __builtin_amdgcn_s_barrier();
    asm volatile("s_waitcnt lgkmcnt(0)" ::: "memory");
    __builtin_amdgcn_sched_barrier(0);
    __builtin_amdgcn_s_setprio(1);
#pragma unroll
    for (int m = 0; m < MFRAG / 2; m++)
#pragma unroll
      for (int n = 0; n < 2; n++) {
        acc[m][n] = __builtin_amdgcn_mfma_f32_16x16x32_bf16(Af[m][0], Bfv[n][0], acc[m][n], 0, 0, 0);
        acc[m][n] = __builtin_amdgcn_mfma_f32_16x16x32_bf16(Af[m][1], Bfv[n][1], acc[m][n], 0, 0, 0);
      }
    __builtin_amdgcn_s_setprio(0);
    __builtin_amdgcn_s_barrier();
#pragma unroll
    for (int m = 0; m < MFRAG / 2; m++) { Af[m][0] = ldA(bcur, MFRAG / 2 + m, 0); Af[m][1] = ldA(bcur, MFRAG / 2 + m, 1); }
    if (pf) stageB(bpf, (tt + 2) * 64);
    if (tt + 1 < NT) {
      if constexpr (L == 6) asm volatile("s_waitcnt vmcnt(6)" ::: "memory");
      else                  asm volatile("s_waitcnt vmcnt(4)" ::: "memory");
    } else {
      asm volatile("s_waitcnt vmcnt(0)" ::: "memory");
    }
    __builtin_amdgcn_s_barrier();
    asm volatile("s_waitcnt lgkmcnt(0)" ::: "memory");
    __builtin_amdgcn_sched_barrier(0);
    __builtin_amdgcn_s_setprio(1);
#pragma unroll
    for (int m = 0; m < MFRAG / 2; m++)
#pragma unroll
      for (int n = 0; n < 2; n++) {
        acc[MFRAG / 2 + m][n] = __builtin_amdgcn_mfma_f32_16x16x32_bf16(Af[m][0], Bfv[n][0], acc[MFRAG / 2 + m][n], 0, 0, 0);
        acc[MFRAG / 2 + m][n] = __builtin_amdgcn_mfma_f32_16x16x32_bf16(Af[m][1], Bfv[n][1], acc[MFRAG / 2 + m][n], 0, 0, 0);
      }
    __builtin_amdgcn_s_setprio(0);
    __builtin_amdgcn_s_barrier();
    bcur = bcur == 2 ? 0 : bcur + 1;
  }

#pragma unroll
  for (int m = 0; m < MFRAG; m++)
#pragma unroll
    for (int n = 0; n < 2; n++)
#pragma unroll
      for (int j = 0; j < 4; j++) {
        int row = row0 + wr * (BM / 2) + m * 16 + kg * 4 + j;
        int col = col0 + wc * 32 + n * 16 + rl;
        float v = acc[m][n][j] + bias[col];
        v = fmaxf(v, 0.f);
        if (MODE == 1) ((unsigned short*)outp)[(long)row * ldout + col] = f2b(v);
        else           ((float*)outp)[(long)row * ldout + col] = v;
      }
}

// ---------------- 8-phase 256x256 GEMM (m201 geometry; L0/L1) ----------------
// 512 thr = 8 waves (2M x 4N), per-wave 128x64 (acc[8][4]). BK=64, 2 K-tiles
// per iteration, 8 phases; each phase: {ds_read subtile || stage half-tiles}
// -> s_barrier -> lgkmcnt(0) -> 16 MFMA (setprio) -> s_barrier.
// Counted vmcnt(6) at ph3/ph7 BEFORE the barrier pair (drain is 2 barriers
// ahead of dependent reads -> race-free); never 0 in the main loop.
// Half-tile stream & liveness (verified): ph0: A-hi(t+1); ph2: B-lo(t+2);
// ph3: B-hi,A-lo(t+2)+vmcnt6; ph4: A-hi(t+2); ph6/ph7: tile t+3 (guarded)+vmcnt6.
// Swizzle: 16B chunk c of row r stored at c^(r&7); pre-swizzled global source
// (linear global_load_lds dest) + same XOR on ds_read.
template<int MODE>
__global__ __launch_bounds__(512, 2)
void gemm8ph(const unsigned short* __restrict__ A1, int lda1, int K1,
             const unsigned short* __restrict__ A2, int lda2, int K2,
             const unsigned short* __restrict__ Bt1, int ldb1,
             const unsigned short* __restrict__ Bt2, int ldb2,
             const float* __restrict__ bias,
             void* __restrict__ outp, int ldout) {
  constexpr int AT = 256 * 64;   // ushorts per operand buffer (32 KB)
  __shared__ __attribute__((aligned(16))) unsigned short lds[4 * AT];  // 128 KiB

  const int t = threadIdx.x;
  const int lane = t & 63, wave = t >> 6;
  const int wr = wave >> 2, wc = wave & 3;            // 2M x 4N
  const int rl = lane & 15, kg = lane >> 4;
  const int row0 = blockIdx.x * 256, col0 = blockIdx.y * 256;
  const int sr = t >> 3;                              // staging row 0..63
  const int sk = ((t & 7) ^ (sr & 7)) * 8;            // pre-swizzled source k

  f32x4 acc[8][4];
#pragma unroll
  for (int m = 0; m < 8; m++)
#pragma unroll
    for (int n = 0; n < 4; n++) acc[m][n] = (f32x4){0.f, 0.f, 0.f, 0.f};

  // stage one half-tile (128 rows x 64 k = 16 KB, 2 loads/thread)
  auto stageHalf = [&](int buf, int isB, int rowOff, int tile) {
    int kt = tile * 64;
    const unsigned short* src; long ld; int kl;
    if (!isB) { if (kt < K1) { src = A1; ld = lda1; kl = kt; } else { src = A2; ld = lda2; kl = kt - K1; } }
    else      { if (kt < K1) { src = Bt1; ld = ldb1; kl = kt; } else { src = Bt2; ld = ldb2; kl = kt - K1; } }
    const int org = isB ? col0 : row0;
    unsigned short* d = &lds[(isB * 2 + buf) * AT + rowOff * 64 + t * 8];
    const unsigned short* s = src + (long)(org + rowOff + sr) * ld + kl + sk;
    lds_load16(s, d);
    lds_load16(s + 64 * ld, d + 4096);   // rows sr+64..: (r&7) unchanged
  };

  bf16x8 Af[4][2], Bf[4][2];
  auto readA = [&](int buf, int mh) {
#pragma unroll
    for (int mf = 0; mf < 4; mf++) {
      int lr = wr * 128 + mh * 64 + mf * 16 + rl;
#pragma unroll
      for (int ks = 0; ks < 2; ks++)
        Af[mf][ks] = *(const bf16x8*)&lds[buf * AT + lr * 64 + (((ks * 4 + kg) ^ (lr & 7))) * 8];
    }
  };
  auto readB = [&](int buf, int nh) {
#pragma unroll
    for (int nfl = 0; nfl < 2; nfl++) {
      int cr = wc * 64 + (nh * 2 + nfl) * 16 + rl;
#pragma unroll
      for (int ks = 0; ks < 2; ks++)
        Bf[nh * 2 + nfl][ks] = *(const bf16x8*)&lds[(2 + buf) * AT + cr * 64 + (((ks * 4 + kg) ^ (cr & 7))) * 8];
    }
  };
  auto mmaQ = [&](int mh, int nh) {
    __builtin_amdgcn_s_setprio(1);
#pragma unroll
    for (int mf = 0; mf < 4; mf++)
#pragma unroll
      for (int nfl = 0; nfl < 2; nfl++) {
        acc[mh*4+mf][nh*2+nfl] = __builtin_amdgcn_mfma_f32_16x16x32_bf16(Af[mf][0], Bf[nh*2+nfl][0], acc[mh*4+mf][nh*2+nfl], 0, 0, 0);
        acc[mh*4+mf][nh*2+nfl] = __builtin_amdgcn_mfma_f32_16x16x32_bf16(Af[mf][1], Bf[nh*2+nfl][1], acc[mh*4+mf][nh*2+nfl], 0, 0, 0);
      }
    __builtin_amdgcn_s_setprio(0);
  };
#define BAR()  __builtin_amdgcn_s_barrier()
#define LGKM0() do { asm volatile("s_waitcnt lgkmcnt(0)" ::: "memory"); __builtin_amdgcn_sched_barrier(0); } while (0)

  const int NT = (K1 + K2) / 64;     // odd by construction (19 or 11)
  const int NH = (NT - 1) / 2;

  // prologue: tile0 (4 units) + tile1 first 3 units; keep 3 newest in flight
  stageHalf(0, 1, 0, 0);  stageHalf(0, 1, 128, 0);
  stageHalf(0, 0, 0, 0);  stageHalf(0, 0, 128, 0);
  stageHalf(1, 1, 0, 1);  stageHalf(1, 1, 128, 1);
  stageHalf(1, 0, 0, 1);
  asm volatile("s_waitcnt vmcnt(6)" ::: "memory");
  BAR();

  for (int i = 0; i < NH; ++i) {
    const int tb = 2 * i;
    // ph0: tile tb, Q(m-lo, n-lo)
    stageHalf(1, 0, 128, tb + 1);                 // A-hi(t+1) -> buf1
    readA(0, 0); readB(0, 0);
    BAR(); LGKM0(); mmaQ(0, 0); BAR();
    // ph1: Q(m-lo, n-hi)
    readB(0, 1);
    BAR(); LGKM0(); mmaQ(0, 1); BAR();
    // ph2: Q(m-hi, n-lo)
    readA(0, 1);
    stageHalf(0, 1, 0, tb + 2);                   // B-lo(t+2) -> buf0
    BAR(); LGKM0(); mmaQ(1, 0); BAR();
    // ph3: Q(m-hi, n-hi); drain tile tb+1 (keep 3 newest units)
    stageHalf(0, 1, 128, tb + 2);                 // B-hi(t+2)
    stageHalf(0, 0, 0, tb + 2);                   // A-lo(t+2)
    asm volatile("s_waitcnt vmcnt(6)" ::: "memory");
    BAR(); mmaQ(1, 1); BAR();
    // ph4: tile tb+1, Q(m-lo, n-lo)
    stageHalf(0, 0, 128, tb + 2);                 // A-hi(t+2) -> buf0
    readA(1, 0); readB(1, 0);
    BAR(); LGKM0(); mmaQ(0, 0); BAR();
    // ph5: Q(m-lo, n-hi)
    readB(1, 1);
    BAR(); LGKM0(); mmaQ(0, 1); BAR();
    // ph6: Q(m-hi, n-lo)
    readA(1, 1);
    if (i < NH - 1) stageHalf(1, 1, 0, tb + 3);   // B-lo(t+3) -> buf1
    BAR(); LGKM0(); mmaQ(1, 0); BAR();
    // ph7: Q(m-hi, n-hi); drain tile tb+2
    if (i < NH - 1) { stageHalf(1, 1, 128, tb + 3); stageHalf(1, 0, 0, tb + 3); }
    asm volatile("s_waitcnt vmcnt(6)" ::: "memory");
    BAR(); mmaQ(1, 1); BAR();
  }

  // tail: tile NT-1 (even -> buf0), fully drained
  asm volatile("s_waitcnt vmcnt(0)" ::: "memory");
  BAR();
  readA(0, 0); readB(0, 0); readB(0, 1);
  LGKM0();
  mmaQ(0, 0); mmaQ(0, 1);
  readA(0, 1);
  LGKM0();
  mmaQ(1, 0); mmaQ(1, 1);

#undef BAR
#undef LGKM0

  // epilogue
#pragma unroll
  for (int m = 0; m < 8; m++)
#pragma unroll
    for (int n = 0; n < 4; n++)
#pragma unroll
      for (int j = 0; j < 4; j++) {
        int row = row0 + wr * 128 + m * 16 + kg * 4 + j;
        int col = col0 + wc * 64 + n * 16 + rl;
        float v = acc[m][n][j] + bias[col];
        v = fmaxf(v, 0.f);
        if (MODE == 1) ((unsigned short*)outp)[(long)row * ldout + col] = f2b(v);
        else           ((float*)outp)[(long)row * ldout + col] = v;
      }
}

// ---------------- launch ----------------

extern "C" void kernel_launch(void* const* d_in, const int* in_sizes, int n_in,
                              void* d_out, int out_size, void* d_ws, size_t ws_size,
                              hipStream_t stream) {
  (void)in_sizes; (void)n_in; (void)out_size; (void)ws_size;
  const float* dnn = (const float*)d_in[0];
  const int*   dom = (const int*)d_in[1];
  const float* emb = (const float*)d_in[2];
  const float* gW  = (const float*)d_in[3];
  const float* gb  = (const float*)d_in[4];
  const float* Wm[3]  = {(const float*)d_in[5],  (const float*)d_in[10], (const float*)d_in[15]};
  const float* bm[3]  = {(const float*)d_in[6],  (const float*)d_in[11], (const float*)d_in[16]};
  const float* Am[3]  = {(const float*)d_in[7],  (const float*)d_in[12], (const float*)d_in[17]};
  const float* Bm[3]  = {(const float*)d_in[8],  (const float*)d_in[13], (const float*)d_in[18]};
  const float* lbm[3] = {(const float*)d_in[9],  (const float*)d_in[14], (const float*)d_in[19]};

  const int M = M_ROWS;
  const int dIn[3]  = {1024, 1024, 512};
  const int dOutN[3] = {1024, 512, 256};

  char* p = (char*)d_ws;
  auto carve = [&](size_t bytes) { char* r = p; p += (bytes + 255) & ~(size_t)255; return r; };
  float* gate = (float*)carve((size_t)M * 8 * sizeof(float));
  unsigned short* xb0 = (unsigned short*)carve((size_t)M * 1024 * 2);
  unsigned short* xb1 = (unsigned short*)carve((size_t)M * 1024 * 2);
  unsigned short* tg  = (unsigned short*)carve((size_t)M * KAUG * 2);
  unsigned short *Wt[3], *Aft[3], *Bft[3];
  for (int l = 0; l < 3; l++) {
    Wt[l]  = (unsigned short*)carve((size_t)dOutN[l] * dIn[l] * 2);
    Aft[l] = (unsigned short*)carve((size_t)128 * dIn[l] * 2);
    Bft[l] = (unsigned short*)carve((size_t)dOutN[l] * KAUG * 2);
  }

  gate_kernel<<<M / 256, 256, 0, stream>>>(dom, emb, gW, gb, gate);
  {
    int n4 = M * 1024 / 4;
    f32_to_bf16_vec<<<(n4 + 255) / 256, 256, 0, stream>>>(dnn, xb0, n4);
  }
  for (int l = 0; l < 3; l++) {
    build_wt_t<<<dim3(dOutN[l] / 32, dIn[l] / 32), 256, 0, stream>>>(Wm[l], Wt[l], dIn[l], dOutN[l]);
    build_aft_t<<<dim3(dIn[l] / 64, 8), 256, 0, stream>>>(Am[l], Aft[l], dIn[l]);
    build_bft_t<<<dim3(dOutN[l] / 32, KAUG / 32), 256, 0, stream>>>(Bm[l], lbm[l], Bft[l], dOutN[l]);
  }
  aug_fill<<<(M * 64) / 256, 256, 0, stream>>>(gate, tg);

  const unsigned short* xin = xb0;
  for (int l = 0; l < 3; l++) {
    int K1 = dIn[l], N = dOutN[l];
    // tg[:, :128] = gate-scaled x @ A_flat   (64-row tiles -> 256 blocks)
    gemm2ph<2><<<dim3(M / 64, 1), 256, 0, stream>>>(
        xin, K1, K1, Aft[l], gate, (void*)tg, KAUG);
    // out = relu(x @ W + tg_aug @ B_aug + bias)
    if (l == 0)
      gemm8ph<1><<<dim3(M / 256, N / 256), 512, 0, stream>>>(
          xin, K1, K1, tg, KAUG, KAUG, Wt[l], K1, Bft[l], KAUG, bm[l], (void*)xb1, N);
    else if (l == 1)
      gemm8ph<1><<<dim3(M / 256, N / 256), 512, 0, stream>>>(
          xin, K1, K1, tg, KAUG, KAUG, Wt[l], K1, Bft[l], KAUG, bm[l], (void*)xb0, N);
    else
      gemm_mn<2, 128><<<dim3(M / 128, N / 128), 512, 0, stream>>>(
          xin, K1, K1, tg, KAUG, KAUG, Wt[l], K1, Bft[l], KAUG, bm[l], d_out, N);
    xin = (l == 0) ? xb1 : xb0;
  }
}

// Round 7
// 158.215 us; speedup vs baseline: 1.1862x; 1.1862x over previous
//
#include <hip/hip_runtime.h>
#include <hip/hip_bf16.h>
#include <stdint.h>

#define KAUG 192   // 128 LoRA cols + 8 gate cols + 56 zero pad (multiple of 64)
#define M_ROWS 16384

typedef __attribute__((ext_vector_type(8))) __bf16 bf16x8;
typedef __attribute__((ext_vector_type(4))) float f32x4;

__device__ __forceinline__ unsigned short f2b(float f) {
  unsigned int u = __builtin_bit_cast(unsigned int, f);
  u = (u + 0x7fffu + ((u >> 16) & 1u)) >> 16;
  return (unsigned short)u;
}

__device__ __forceinline__ void lds_load16(const unsigned short* g, unsigned short* l) {
  __builtin_amdgcn_global_load_lds(
      (const __attribute__((address_space(1))) void*)g,
      (__attribute__((address_space(3))) void*)l, 16, 0, 0);
}

template<int N> __device__ __forceinline__ void vmcnt_wait() {
  if constexpr (N == 0)      asm volatile("s_waitcnt vmcnt(0)" ::: "memory");
  else if constexpr (N == 3) asm volatile("s_waitcnt vmcnt(3)" ::: "memory");
  else if constexpr (N == 4) asm volatile("s_waitcnt vmcnt(4)" ::: "memory");
  else if constexpr (N == 6) asm volatile("s_waitcnt vmcnt(6)" ::: "memory");
  else                       asm volatile("s_waitcnt vmcnt(8)" ::: "memory");
}

// ---------------- prep kernels ----------------

__global__ void gate_kernel(const int* __restrict__ dom, const float* __restrict__ emb,
                            const float* __restrict__ gW, const float* __restrict__ gb,
                            float* __restrict__ gate) {
  int i = blockIdx.x * blockDim.x + threadIdx.x;
  int d = dom[i];
  float e0 = emb[d*4+0], e1 = emb[d*4+1], e2 = emb[d*4+2], e3 = emb[d*4+3];
  float l[8]; float mx = -1e30f;
#pragma unroll
  for (int j = 0; j < 8; j++) {
    l[j] = e0*gW[j] + e1*gW[8+j] + e2*gW[16+j] + e3*gW[24+j] + gb[j];
    mx = fmaxf(mx, l[j]);
  }
  float s = 0.f;
#pragma unroll
  for (int j = 0; j < 8; j++) { l[j] = __expf(l[j] - mx); s += l[j]; }
  float inv = 1.0f / s;
#pragma unroll
  for (int j = 0; j < 8; j++) gate[i*8+j] = l[j] * inv;
}

__global__ void f32_to_bf16_vec(const float* __restrict__ in, unsigned short* __restrict__ out, int n4) {
  int i = blockIdx.x * blockDim.x + threadIdx.x;
  if (i >= n4) return;
  float4 v = ((const float4*)in)[i];
  ushort4 o;
  o.x = f2b(v.x); o.y = f2b(v.y); o.z = f2b(v.z); o.w = f2b(v.w);
  ((ushort4*)out)[i] = o;
}

// LDS-tiled transpose: Wt[n*K+k] = bf16(W[k*N+n]); both sides coalesced.
__global__ void build_wt_t(const float* __restrict__ W, unsigned short* __restrict__ Wt,
                           int K, int N) {
  __shared__ float tl[32][33];
  int n0 = blockIdx.x * 32, k0 = blockIdx.y * 32;
  int tx = threadIdx.x & 31, ty = threadIdx.x >> 5;   // 256 thr: ty 0..7
#pragma unroll
  for (int i = 0; i < 32; i += 8)
    tl[ty + i][tx] = W[(long)(k0 + ty + i) * N + n0 + tx];
  __syncthreads();
#pragma unroll
  for (int i = 0; i < 32; i += 8)
    Wt[(long)(n0 + ty + i) * K + k0 + tx] = f2b(tl[tx][ty + i]);
}

// Aft[(e*16+r)*P + p] = bf16(A[e][p][r]); LDS-tiled, coalesced.
__global__ void build_aft_t(const float* __restrict__ A, unsigned short* __restrict__ Aft, int P) {
  __shared__ float tl[64][17];
  int e = blockIdx.y; long p0 = (long)blockIdx.x * 64;
  int t = threadIdx.x;
#pragma unroll
  for (int pass = 0; pass < 4; pass++) {
    int idx = t + pass * 256;           // 0..1023
    int pl = idx >> 4, r = idx & 15;
    tl[pl][r] = A[((long)e * P + p0 + pl) * 16 + r];
  }
  __syncthreads();
#pragma unroll
  for (int pass = 0; pass < 4; pass++) {
    int idx = t + pass * 256;
    int r = idx >> 6, pl = idx & 63;
    Aft[(long)(e * 16 + r) * P + p0 + pl] = f2b(tl[pl][r]);
  }
}

// Bft[n*KAUG + kk]: kk<128 -> B_flat[kk*H+n]; kk in [128,136) -> lb[kk-128][n]; else 0.
__global__ void build_bft_t(const float* __restrict__ Bm, const float* __restrict__ lb,
                            unsigned short* __restrict__ Bft, int H) {
  __shared__ float tl[32][33];
  int n0 = blockIdx.x * 32, kk0 = blockIdx.y * 32;
  int tx = threadIdx.x & 31, ty = threadIdx.x >> 5;
#pragma unroll
  for (int i = 0; i < 32; i += 8) {
    int kk = kk0 + ty + i;
    float v;
    if (kk < 128)       v = Bm[(long)kk * H + n0 + tx];
    else if (kk < 136)  v = lb[(long)(kk - 128) * H + n0 + tx];
    else                v = 0.f;
    tl[ty + i][tx] = v;
  }
  __syncthreads();
#pragma unroll
  for (int i = 0; i < 32; i += 8)
    Bft[(long)(n0 + ty + i) * KAUG + kk0 + tx] = f2b(tl[tx][ty + i]);
}

// tg[b][128+j]: j<8 -> gate[b][j]; j in [8,64) -> 0
__global__ void aug_fill(const float* __restrict__ gate, unsigned short* __restrict__ tg) {
  int i = blockIdx.x * blockDim.x + threadIdx.x;  // M*64 threads
  int j = i & 63; int b = i >> 6;
  float v = (j < 8) ? gate[b*8 + j] : 0.f;
  tg[(long)b * KAUG + 128 + j] = f2b(v);
}

// ---------------- fine-phase 128-wide GEMM (x@A, L1 main, L2 main) ----------------
// BM x 128 tile, BK=64, 512 threads = 8 waves (2M x 4N), per-wave BM/2 x 32.
// 3 LDS buffers; tile t+2 staged during tile t -> 2-tile-deep prefetch;
// counted vmcnt(L) once per tile (never 0 in-loop).
// MODE 0: out = bf16(C * gate[row][col>>4]); MODE 1: bf16(relu(C+bias));
// MODE 2: f32(relu(C+bias)).
template<int MODE, int BM>
__global__ __launch_bounds__(512)
void gemm_mn(const unsigned short* __restrict__ A1, int lda1, int K1,
             const unsigned short* __restrict__ A2, int lda2, int K2,
             const unsigned short* __restrict__ Bt1, int ldb1,
             const unsigned short* __restrict__ Bt2, int ldb2,
             const float* __restrict__ bias,
             const float* __restrict__ gate,
             void* __restrict__ outp, int ldout) {
  constexpr int MFRAG = BM / 32;
  constexpr int ATOT = BM * 64;
  constexpr int BTOT = 128 * 64;
  constexpr int LA = BM / 64;             // A loads per thread per tile (1/2/4)
  constexpr int L = LA + 2;               // total loads per thread per tile
  __shared__ __attribute__((aligned(16))) unsigned short lds[3 * ATOT + 3 * BTOT];

  const int t = threadIdx.x;
  const int lane = t & 63, wave = t >> 6;
  const int wr = wave >> 2, wc = wave & 3;
  const int rl = lane & 15, kg = lane >> 4;
  const int row0 = blockIdx.x * BM, col0 = blockIdx.y * 128;

  const int sr = t >> 3;
  const int sk = ((t & 7) ^ (sr & 7)) * 8;

  f32x4 acc[MFRAG][2];
#pragma unroll
  for (int m = 0; m < MFRAG; m++)
#pragma unroll
    for (int n = 0; n < 2; n++) acc[m][n] = (f32x4){0.f, 0.f, 0.f, 0.f};

  auto stageA = [&](int buf, int kt) {
    const unsigned short* src; long ld; int kl;
    if (kt < K1) { src = A1; ld = lda1; kl = kt; }
    else         { src = A2; ld = lda2; kl = kt - K1; }
    unsigned short* d = &lds[buf * ATOT + t * 8];
    const unsigned short* s = src + (long)(row0 + sr) * ld + kl + sk;
#pragma unroll
    for (int i = 0; i < LA; i++)
      lds_load16(s + (long)(i * 64) * ld, d + i * 4096);
  };
  auto stageB = [&](int buf, int kt) {
    const unsigned short* src; long ld; int kl;
    if (kt < K1) { src = Bt1; ld = ldb1; kl = kt; }
    else         { src = Bt2; ld = ldb2; kl = kt - K1; }
    unsigned short* d = &lds[3 * ATOT + buf * BTOT + t * 8];
    const unsigned short* s = src + (long)(col0 + sr) * ld + kl + sk;
    lds_load16(s, d);
    lds_load16(s + 64 * ld, d + 4096);
  };
  auto ldA = [&](int buf, int mg, int ks) {
    int lr = wr * (BM / 2) + mg * 16 + rl;
    int sc = (ks * 4 + kg) ^ (lr & 7);
    return *(const bf16x8*)&lds[buf * ATOT + lr * 64 + sc * 8];
  };
  auto ldB = [&](int buf, int n, int ks) {
    int cr = wc * 32 + n * 16 + rl;
    int sc = (ks * 4 + kg) ^ (cr & 7);
    return *(const bf16x8*)&lds[3 * ATOT + buf * BTOT + cr * 64 + sc * 8];
  };

  const int Ktot = K1 + K2;
  const int NT = Ktot / 64;

  stageA(0, 0); stageB(0, 0);
  stageA(1, 64); stageB(1, 64);
  vmcnt_wait<L>();
  __builtin_amdgcn_s_barrier();

  int bcur = 0;
  bf16x8 Bfv[2][2];
  for (int tt = 0; tt < NT; ++tt) {
    int bpf = bcur + 2; if (bpf > 2) bpf -= 3;
    const bool pf = (tt + 2 < NT);
    bf16x8 Af[(MFRAG + 1) / 2][2];
#pragma unroll
    for (int m = 0; m < MFRAG / 2; m++) { Af[m][0] = ldA(bcur, m, 0); Af[m][1] = ldA(bcur, m, 1); }
#pragma unroll
    for (int n = 0; n < 2; n++) { Bfv[n][0] = ldB(bcur, n, 0); Bfv[n][1] = ldB(bcur, n, 1); }
    if (pf) stageA(bpf, (tt + 2) * 64);
    __builtin_amdgcn_s_barrier();
    asm volatile("s_waitcnt lgkmcnt(0)" ::: "memory");
    __builtin_amdgcn_sched_barrier(0);
    __builtin_amdgcn_s_setprio(1);
#pragma unroll
    for (int m = 0; m < MFRAG / 2; m++)
#pragma unroll
      for (int n = 0; n < 2; n++) {
        acc[m][n] = __builtin_amdgcn_mfma_f32_16x16x32_bf16(Af[m][0], Bfv[n][0], acc[m][n], 0, 0, 0);
        acc[m][n] = __builtin_amdgcn_mfma_f32_16x16x32_bf16(Af[m][1], Bfv[n][1], acc[m][n], 0, 0, 0);
      }
    __builtin_amdgcn_s_setprio(0);
    __builtin_amdgcn_s_barrier();
#pragma unroll
    for (int m = 0; m < MFRAG / 2; m++) { Af[m][0] = ldA(bcur, MFRAG / 2 + m, 0); Af[m][1] = ldA(bcur, MFRAG / 2 + m, 1); }
    if (pf) stageB(bpf, (tt + 2) * 64);
    if (tt + 1 < NT) vmcnt_wait<L>();
    else             vmcnt_wait<0>();
    __builtin_amdgcn_s_barrier();
    asm volatile("s_waitcnt lgkmcnt(0)" ::: "memory");
    __builtin_amdgcn_sched_barrier(0);
    __builtin_amdgcn_s_setprio(1);
#pragma unroll
    for (int m = 0; m < MFRAG / 2; m++)
#pragma unroll
      for (int n = 0; n < 2; n++) {
        acc[MFRAG / 2 + m][n] = __builtin_amdgcn_mfma_f32_16x16x32_bf16(Af[m][0], Bfv[n][0], acc[MFRAG / 2 + m][n], 0, 0, 0);
        acc[MFRAG / 2 + m][n] = __builtin_amdgcn_mfma_f32_16x16x32_bf16(Af[m][1], Bfv[n][1], acc[MFRAG / 2 + m][n], 0, 0, 0);
      }
    __builtin_amdgcn_s_setprio(0);
    __builtin_amdgcn_s_barrier();
    bcur = bcur == 2 ? 0 : bcur + 1;
  }

#pragma unroll
  for (int m = 0; m < MFRAG; m++)
#pragma unroll
    for (int n = 0; n < 2; n++)
#pragma unroll
      for (int j = 0; j < 4; j++) {
        int row = row0 + wr * (BM / 2) + m * 16 + kg * 4 + j;
        int col = col0 + wc * 32 + n * 16 + rl;
        float v = acc[m][n][j];
        if (MODE == 0) {
          v *= gate[row * 8 + (col >> 4)];
          ((unsigned short*)outp)[(long)row * ldout + col] = f2b(v);
        } else {
          v += bias[col];
          v = fmaxf(v, 0.f);
          if (MODE == 1) ((unsigned short*)outp)[(long)row * ldout + col] = f2b(v);
          else           ((float*)outp)[(long)row * ldout + col] = v;
        }
      }
}

// ---------------- 8-phase 256x256 GEMM (m201 geometry; L0 main) ----------------
// 512 thr = 8 waves (2M x 4N), per-wave 128x64 (acc[8][4]). BK=64, 2 K-tiles
// per iteration, 8 phases; counted vmcnt(6) at ph3/ph7 before the barrier
// pair; never 0 in the main loop. Swizzle: chunk c of row r at c^(r&7).
template<int MODE>
__global__ __launch_bounds__(512, 2)
void gemm8ph(const unsigned short* __restrict__ A1, int lda1, int K1,
             const unsigned short* __restrict__ A2, int lda2, int K2,
             const unsigned short* __restrict__ Bt1, int ldb1,
             const unsigned short* __restrict__ Bt2, int ldb2,
             const float* __restrict__ bias,
             void* __restrict__ outp, int ldout) {
  constexpr int AT = 256 * 64;   // ushorts per operand buffer (32 KB)
  __shared__ __attribute__((aligned(16))) unsigned short lds[4 * AT];  // 128 KiB

  const int t = threadIdx.x;
  const int lane = t & 63, wave = t >> 6;
  const int wr = wave >> 2, wc = wave & 3;            // 2M x 4N
  const int rl = lane & 15, kg = lane >> 4;
  const int row0 = blockIdx.x * 256, col0 = blockIdx.y * 256;
  const int sr = t >> 3;                              // staging row 0..63
  const int sk = ((t & 7) ^ (sr & 7)) * 8;            // pre-swizzled source k

  f32x4 acc[8][4];
#pragma unroll
  for (int m = 0; m < 8; m++)
#pragma unroll
    for (int n = 0; n < 4; n++) acc[m][n] = (f32x4){0.f, 0.f, 0.f, 0.f};

  auto stageHalf = [&](int buf, int isB, int rowOff, int tile) {
    int kt = tile * 64;
    const unsigned short* src; long ld; int kl;
    if (!isB) { if (kt < K1) { src = A1; ld = lda1; kl = kt; } else { src = A2; ld = lda2; kl = kt - K1; } }
    else      { if (kt < K1) { src = Bt1; ld = ldb1; kl = kt; } else { src = Bt2; ld = ldb2; kl = kt - K1; } }
    const int org = isB ? col0 : row0;
    unsigned short* d = &lds[(isB * 2 + buf) * AT + rowOff * 64 + t * 8];
    const unsigned short* s = src + (long)(org + rowOff + sr) * ld + kl + sk;
    lds_load16(s, d);
    lds_load16(s + 64 * ld, d + 4096);
  };

  bf16x8 Af[4][2], Bf[4][2];
  auto readA = [&](int buf, int mh) {
#pragma unroll
    for (int mf = 0; mf < 4; mf++) {
      int lr = wr * 128 + mh * 64 + mf * 16 + rl;
#pragma unroll
      for (int ks = 0; ks < 2; ks++)
        Af[mf][ks] = *(const bf16x8*)&lds[buf * AT + lr * 64 + (((ks * 4 + kg) ^ (lr & 7))) * 8];
    }
  };
  auto readB = [&](int buf, int nh) {
#pragma unroll
    for (int nfl = 0; nfl < 2; nfl++) {
      int cr = wc * 64 + (nh * 2 + nfl) * 16 + rl;
#pragma unroll
      for (int ks = 0; ks < 2; ks++)
        Bf[nh * 2 + nfl][ks] = *(const bf16x8*)&lds[(2 + buf) * AT + cr * 64 + (((ks * 4 + kg) ^ (cr & 7))) * 8];
    }
  };
  auto mmaQ = [&](int mh, int nh) {
    __builtin_amdgcn_s_setprio(1);
#pragma unroll
    for (int mf = 0; mf < 4; mf++)
#pragma unroll
      for (int nfl = 0; nfl < 2; nfl++) {
        acc[mh*4+mf][nh*2+nfl] = __builtin_amdgcn_mfma_f32_16x16x32_bf16(Af[mf][0], Bf[nh*2+nfl][0], acc[mh*4+mf][nh*2+nfl], 0, 0, 0);
        acc[mh*4+mf][nh*2+nfl] = __builtin_amdgcn_mfma_f32_16x16x32_bf16(Af[mf][1], Bf[nh*2+nfl][1], acc[mh*4+mf][nh*2+nfl], 0, 0, 0);
      }
    __builtin_amdgcn_s_setprio(0);
  };
#define BAR()  __builtin_amdgcn_s_barrier()
#define LGKM0() do { asm volatile("s_waitcnt lgkmcnt(0)" ::: "memory"); __builtin_amdgcn_sched_barrier(0); } while (0)

  const int NT = (K1 + K2) / 64;     // odd by construction (19)
  const int NH = (NT - 1) / 2;

  stageHalf(0, 1, 0, 0);  stageHalf(0, 1, 128, 0);
  stageHalf(0, 0, 0, 0);  stageHalf(0, 0, 128, 0);
  stageHalf(1, 1, 0, 1);  stageHalf(1, 1, 128, 1);
  stageHalf(1, 0, 0, 1);
  asm volatile("s_waitcnt vmcnt(6)" ::: "memory");
  BAR();

  for (int i = 0; i < NH; ++i) {
    const int tb = 2 * i;
    stageHalf(1, 0, 128, tb + 1);                 // A-hi(t+1) -> buf1
    readA(0, 0); readB(0, 0);
    BAR(); LGKM0(); mmaQ(0, 0); BAR();
    readB(0, 1);
    BAR(); LGKM0(); mmaQ(0, 1); BAR();
    readA(0, 1);
    stageHalf(0, 1, 0, tb + 2);                   // B-lo(t+2) -> buf0
    BAR(); LGKM0(); mmaQ(1, 0); BAR();
    stageHalf(0, 1, 128, tb + 2);                 // B-hi(t+2)
    stageHalf(0, 0, 0, tb + 2);                   // A-lo(t+2)
    asm volatile("s_waitcnt vmcnt(6)" ::: "memory");
    BAR(); mmaQ(1, 1); BAR();
    stageHalf(0, 0, 128, tb + 2);                 // A-hi(t+2) -> buf0
    readA(1, 0); readB(1, 0);
    BAR(); LGKM0(); mmaQ(0, 0); BAR();
    readB(1, 1);
    BAR(); LGKM0(); mmaQ(0, 1); BAR();
    readA(1, 1);
    if (i < NH - 1) stageHalf(1, 1, 0, tb + 3);   // B-lo(t+3) -> buf1
    BAR(); LGKM0(); mmaQ(1, 0); BAR();
    if (i < NH - 1) { stageHalf(1, 1, 128, tb + 3); stageHalf(1, 0, 0, tb + 3); }
    asm volatile("s_waitcnt vmcnt(6)" ::: "memory");
    BAR(); mmaQ(1, 1); BAR();
  }

  asm volatile("s_waitcnt vmcnt(0)" ::: "memory");
  BAR();
  readA(0, 0); readB(0, 0); readB(0, 1);
  LGKM0();
  mmaQ(0, 0); mmaQ(0, 1);
  readA(0, 1);
  LGKM0();
  mmaQ(1, 0); mmaQ(1, 1);

#undef BAR
#undef LGKM0

#pragma unroll
  for (int m = 0; m < 8; m++)
#pragma unroll
    for (int n = 0; n < 4; n++)
#pragma unroll
      for (int j = 0; j < 4; j++) {
        int row = row0 + wr * 128 + m * 16 + kg * 4 + j;
        int col = col0 + wc * 64 + n * 16 + rl;
        float v = acc[m][n][j] + bias[col];
        v = fmaxf(v, 0.f);
        if (MODE == 1) ((unsigned short*)outp)[(long)row * ldout + col] = f2b(v);
        else           ((float*)outp)[(long)row * ldout + col] = v;
      }
}

// ---------------- launch ----------------

extern "C" void kernel_launch(void* const* d_in, const int* in_sizes, int n_in,
                              void* d_out, int out_size, void* d_ws, size_t ws_size,
                              hipStream_t stream) {
  (void)in_sizes; (void)n_in; (void)out_size; (void)ws_size;
  const float* dnn = (const float*)d_in[0];
  const int*   dom = (const int*)d_in[1];
  const float* emb = (const float*)d_in[2];
  const float* gW  = (const float*)d_in[3];
  const float* gb  = (const float*)d_in[4];
  const float* Wm[3]  = {(const float*)d_in[5],  (const float*)d_in[10], (const float*)d_in[15]};
  const float* bm[3]  = {(const float*)d_in[6],  (const float*)d_in[11], (const float*)d_in[16]};
  const float* Am[3]  = {(const float*)d_in[7],  (const float*)d_in[12], (const float*)d_in[17]};
  const float* Bm[3]  = {(const float*)d_in[8],  (const float*)d_in[13], (const float*)d_in[18]};
  const float* lbm[3] = {(const float*)d_in[9],  (const float*)d_in[14], (const float*)d_in[19]};

  const int M = M_ROWS;
  const int dIn[3]  = {1024, 1024, 512};
  const int dOutN[3] = {1024, 512, 256};

  char* p = (char*)d_ws;
  auto carve = [&](size_t bytes) { char* r = p; p += (bytes + 255) & ~(size_t)255; return r; };
  float* gate = (float*)carve((size_t)M * 8 * sizeof(float));
  unsigned short* xb0 = (unsigned short*)carve((size_t)M * 1024 * 2);
  unsigned short* xb1 = (unsigned short*)carve((size_t)M * 1024 * 2);
  unsigned short* tg  = (unsigned short*)carve((size_t)M * KAUG * 2);
  unsigned short *Wt[3], *Aft[3], *Bft[3];
  for (int l = 0; l < 3; l++) {
    Wt[l]  = (unsigned short*)carve((size_t)dOutN[l] * dIn[l] * 2);
    Aft[l] = (unsigned short*)carve((size_t)128 * dIn[l] * 2);
    Bft[l] = (unsigned short*)carve((size_t)dOutN[l] * KAUG * 2);
  }

  gate_kernel<<<M / 256, 256, 0, stream>>>(dom, emb, gW, gb, gate);
  {
    int n4 = M * 1024 / 4;
    f32_to_bf16_vec<<<(n4 + 255) / 256, 256, 0, stream>>>(dnn, xb0, n4);
  }
  for (int l = 0; l < 3; l++) {
    build_wt_t<<<dim3(dOutN[l] / 32, dIn[l] / 32), 256, 0, stream>>>(Wm[l], Wt[l], dIn[l], dOutN[l]);
    build_aft_t<<<dim3(dIn[l] / 64, 8), 256, 0, stream>>>(Am[l], Aft[l], dIn[l]);
    build_bft_t<<<dim3(dOutN[l] / 32, KAUG / 32), 256, 0, stream>>>(Bm[l], lbm[l], Bft[l], dOutN[l]);
  }
  aug_fill<<<(M * 64) / 256, 256, 0, stream>>>(gate, tg);

  const unsigned short* xin = xb0;
  for (int l = 0; l < 3; l++) {
    int K1 = dIn[l], N = dOutN[l];
    // tg[:, :128] = gate-scaled x @ A_flat  (deep-pipelined, 256 blocks)
    gemm_mn<0, 64><<<dim3(M / 64, 1), 512, 0, stream>>>(
        xin, K1, K1, nullptr, 0, 0, Aft[l], K1, nullptr, 0, nullptr, gate, (void*)tg, KAUG);
    // out = relu(x @ W + tg_aug @ B_aug + bias)
    if (l == 0)
      gemm8ph<1><<<dim3(M / 256, N / 256), 512, 0, stream>>>(
          xin, K1, K1, tg, KAUG, KAUG, Wt[l], K1, Bft[l], KAUG, bm[l], (void*)xb1, N);
    else if (l == 1)
      gemm_mn<1, 256><<<dim3(M / 256, N / 128), 512, 0, stream>>>(
          xin, K1, K1, tg, KAUG, KAUG, Wt[l], K1, Bft[l], KAUG, bm[l], nullptr, (void*)xb0, N);
    else
      gemm_mn<2, 128><<<dim3(M / 128, N / 128), 512, 0, stream>>>(
          xin, K1, K1, tg, KAUG, KAUG, Wt[l], K1, Bft[l], KAUG, bm[l], nullptr, d_out, N);
    xin = (l == 0) ? xb1 : xb0;
  }
}